// Round 1
// baseline (349.413 us; speedup 1.0000x reference)
//
#include <hip/hip_runtime.h>
#include <math.h>

#define B_DIM 2048
#define C_DIM 32000
#define MARGIN 1.0f
#define NTHREADS 256

typedef float vfloat4 __attribute__((ext_vector_type(4)));

__device__ __forceinline__ float waveReduceSum(float v) {
    #pragma unroll
    for (int off = 32; off > 0; off >>= 1)
        v += __shfl_down(v, off, 64);
    return v;
}

// 6 VALU / element: cmp+addc (rank), cmp+addc (n_pos), max+add (hinge partial)
__device__ __forceinline__ void acc4(vfloat4 v, float gt, float thr,
                                     int& cntG, int& cntP, float& sumM) {
    cntG += (v.x > gt); cntG += (v.y > gt); cntG += (v.z > gt); cntG += (v.w > gt);
    cntP += (v.x > thr); cntP += (v.y > thr); cntP += (v.z > thr); cntP += (v.w > thr);
    sumM += fmaxf(v.x, thr); sumM += fmaxf(v.y, thr);
    sumM += fmaxf(v.z, thr); sumM += fmaxf(v.w, thr);
}

__global__ __launch_bounds__(NTHREADS) void row_loss_kernel(
        const float* __restrict__ scores,
        const int* __restrict__ targets,
        float* __restrict__ row_loss) {
    const int b = blockIdx.x;
    const int tid = threadIdx.x;
    const int lane = tid & 63;
    const int wave = tid >> 6;

    const float* __restrict__ row = scores + (size_t)b * C_DIM;

    // b is uniform -> scalar loads; no barrier needed.
    const int tgt  = targets[b];
    const float gt = row[tgt];
    const float thr = gt - MARGIN;

    int   cntG = 0;    // # scores strictly greater than gt
    int   cntP = 0;    // # scores > thr (incl. target, fixed later)
    float sumM = 0.f;  // sum of max(s, thr); hinge = sumM - C*thr

    const vfloat4* __restrict__ row4 = (const vfloat4*)row;
    // 8000 float4 = 31 full groups of 256 + one 64-wide tail group.
    // Software pipeline, 8 loads in flight. Cached (NOT nontemporal) loads:
    // the 262 MB input marginally fits the 256 MiB Infinity Cache, so any
    // L3 retention across iterations is free upside; streaming cost is
    // identical otherwise.
    vfloat4 buf[8];
    #pragma unroll
    for (int j = 0; j < 8; ++j)
        buf[j] = row4[tid + j * NTHREADS];

    #pragma unroll
    for (int j = 0; j < 31; ++j) {
        vfloat4 v = buf[j & 7];
        if (j + 8 < 31) {
            buf[j & 7] = row4[tid + (j + 8) * NTHREADS];
        } else if (j + 8 == 31) {
            if (tid < 64) buf[j & 7] = row4[7936 + tid];
        }
        acc4(v, gt, thr, cntG, cntP, sumM);
    }
    if (tid < 64) {
        // tail group sits in slot (23 & 7) == 7
        acc4(buf[7], gt, thr, cntG, cntP, sumM);
    }

    float cg = waveReduceSum((float)cntG);
    float cp = waveReduceSum((float)cntP);
    float sm = waveReduceSum(sumM);

    __shared__ float red[4][3];
    if (lane == 0) { red[wave][0] = cg; red[wave][1] = cp; red[wave][2] = sm; }
    __syncthreads();

    if (tid == 0) {
        float tg = 0.f, tp = 0.f, tm = 0.f;
        #pragma unroll
        for (int w = 0; w < 4; ++w) { tg += red[w][0]; tp += red[w][1]; tm += red[w][2]; }
        int rank = (int)tg + 1;              // 1-based rank of ground truth
        float n_pos = tp - 1.0f;             // remove target element
        // hinge over all elements incl. target = sum(max(s,thr)) - C*thr;
        // target contributes exactly (gt - thr) = 1.0f -> subtract it.
        float hinge = (tm - (float)C_DIM * thr) - 1.0f;

        // H(rank): asymptotic expansion (err < 1e-8 for rank>=40), direct sum else.
        float H;
        if (rank >= 40) {
            float n = (float)rank;
            float inv = 1.0f / n;
            H = logf(n) + 0.57721566f + 0.5f * inv - (1.0f / 12.0f) * inv * inv;
        } else {
            H = 0.f;
            for (int k = 1; k <= rank; ++k) H += 1.0f / (float)k;
        }
        // Per-row store instead of a 2048-way same-address atomicAdd chain:
        // avoids L2 serialization + cross-XCD cacheline ping-pong on `out`.
        row_loss[b] = H / (n_pos + 1e-7f) * hinge;
    }
}

__global__ __launch_bounds__(NTHREADS) void finalize_kernel(
        const float* __restrict__ row_loss,
        float* __restrict__ out) {
    const int tid = threadIdx.x;
    float s = 0.f;
    #pragma unroll
    for (int j = 0; j < B_DIM / NTHREADS; ++j)
        s += row_loss[tid + j * NTHREADS];
    s = waveReduceSum(s);
    __shared__ float red[4];
    const int lane = tid & 63;
    const int wave = tid >> 6;
    if (lane == 0) red[wave] = s;
    __syncthreads();
    if (tid == 0)
        *out = (red[0] + red[1] + red[2] + red[3]) * (1.0f / (float)B_DIM);
}

extern "C" void kernel_launch(void* const* d_in, const int* in_sizes, int n_in,
                              void* d_out, int out_size, void* d_ws, size_t ws_size,
                              hipStream_t stream) {
    const float* scores  = (const float*)d_in[0];
    const int*   targets = (const int*)d_in[1];
    float* out = (float*)d_out;
    float* row_loss = (float*)d_ws;   // 2048 floats = 8 KB scratch

    // No hipMemsetAsync needed anymore: finalize_kernel overwrites out.
    row_loss_kernel<<<B_DIM, NTHREADS, 0, stream>>>(scores, targets, row_loss);
    finalize_kernel<<<1, NTHREADS, 0, stream>>>(row_loss, out);
}

// Round 2
// 336.718 us; speedup vs baseline: 1.0377x; 1.0377x over previous
//
#include <hip/hip_runtime.h>
#include <math.h>

#define B_DIM 2048
#define C_DIM 32000
#define MARGIN 1.0f
#define NTHREADS 256

typedef float vfloat4 __attribute__((ext_vector_type(4)));

__device__ __forceinline__ float waveReduceSum(float v) {
    #pragma unroll
    for (int off = 32; off > 0; off >>= 1)
        v += __shfl_down(v, off, 64);
    return v;
}

// 4 VALU / element: cmp (rank, count on SALU via ballot-popcount),
// cmp (n_pos, same), max+add (hinge partial).
// cntG/cntP become WAVE-UNIFORM totals (held in SGPRs by the compiler);
// the int adds ride the scalar pipe and co-issue with VALU/VMEM.
__device__ __forceinline__ void acc4(vfloat4 v, float gt, float thr,
                                     unsigned& cntG, unsigned& cntP, float& sumM) {
    cntG += (unsigned)__popcll(__ballot(v.x > gt));
    cntG += (unsigned)__popcll(__ballot(v.y > gt));
    cntG += (unsigned)__popcll(__ballot(v.z > gt));
    cntG += (unsigned)__popcll(__ballot(v.w > gt));
    cntP += (unsigned)__popcll(__ballot(v.x > thr));
    cntP += (unsigned)__popcll(__ballot(v.y > thr));
    cntP += (unsigned)__popcll(__ballot(v.z > thr));
    cntP += (unsigned)__popcll(__ballot(v.w > thr));
    sumM += fmaxf(v.x, thr); sumM += fmaxf(v.y, thr);
    sumM += fmaxf(v.z, thr); sumM += fmaxf(v.w, thr);
}

__device__ __forceinline__ vfloat4 ntload(const vfloat4* p) {
    return __builtin_nontemporal_load(p);
}

__global__ __launch_bounds__(NTHREADS) void row_loss_kernel(
        const float* __restrict__ scores,
        const int* __restrict__ targets,
        float* __restrict__ out) {
    const int b = blockIdx.x;
    const int tid = threadIdx.x;
    const int lane = tid & 63;
    const int wave = tid >> 6;

    const float* __restrict__ row = scores + (size_t)b * C_DIM;

    // b is uniform -> scalar loads; no barrier needed.
    const int tgt  = targets[b];
    const float gt = row[tgt];
    const float thr = gt - MARGIN;

    unsigned cntG = 0;  // wave-total # scores strictly greater than gt
    unsigned cntP = 0;  // wave-total # scores > thr (incl. target, fixed later)
    float    sumM = 0.f; // per-lane sum of max(s, thr); hinge = sumM - C*thr

    const vfloat4* __restrict__ row4 = (const vfloat4*)row;
    // 8000 float4 = 31 full groups of 256 + one 64-wide tail group.
    // Software pipeline, 8 nontemporal loads always in flight until the tail.
    vfloat4 buf[8];
    #pragma unroll
    for (int j = 0; j < 8; ++j)
        buf[j] = ntload(row4 + tid + j * NTHREADS);

    #pragma unroll
    for (int j = 0; j < 31; ++j) {
        vfloat4 v = buf[j & 7];
        if (j + 8 < 31) {
            buf[j & 7] = ntload(row4 + tid + (j + 8) * NTHREADS);
        } else if (j + 8 == 31) {
            if (tid < 64) buf[j & 7] = ntload(row4 + 7936 + tid);
        }
        acc4(v, gt, thr, cntG, cntP, sumM);
    }
    if (tid < 64) {
        // tail group sits in slot (23 & 7) == 7; wave-uniform branch (wave 0)
        acc4(buf[7], gt, thr, cntG, cntP, sumM);
    }

    // counts are already wave-level totals; only sumM needs a shuffle reduce
    float sm = waveReduceSum(sumM);

    __shared__ float red[4][3];
    if (lane == 0) {
        red[wave][0] = (float)cntG;
        red[wave][1] = (float)cntP;
        red[wave][2] = sm;
    }
    __syncthreads();

    if (tid == 0) {
        float tg = 0.f, tp = 0.f, tm = 0.f;
        #pragma unroll
        for (int w = 0; w < 4; ++w) { tg += red[w][0]; tp += red[w][1]; tm += red[w][2]; }
        int rank = (int)tg + 1;              // 1-based rank of ground truth
        float n_pos = tp - 1.0f;             // remove target element
        // hinge over all elements incl. target = sum(max(s,thr)) - C*thr;
        // target contributes exactly (gt - thr) = 1.0f -> subtract it.
        float hinge = (tm - (float)C_DIM * thr) - 1.0f;

        // H(rank): asymptotic expansion (err < 1e-8 for rank>=40), direct sum else.
        float H;
        if (rank >= 40) {
            float n = (float)rank;
            float inv = 1.0f / n;
            H = logf(n) + 0.57721566f + 0.5f * inv - (1.0f / 12.0f) * inv * inv;
        } else {
            H = 0.f;
            for (int k = 1; k <= rank; ++k) H += 1.0f / (float)k;
        }
        float loss = H / (n_pos + 1e-7f) * hinge;
        atomicAdd(out, loss * (1.0f / (float)B_DIM));
    }
}

extern "C" void kernel_launch(void* const* d_in, const int* in_sizes, int n_in,
                              void* d_out, int out_size, void* d_ws, size_t ws_size,
                              hipStream_t stream) {
    const float* scores  = (const float*)d_in[0];
    const int*   targets = (const int*)d_in[1];
    float* out = (float*)d_out;

    hipMemsetAsync(out, 0, sizeof(float), stream);
    row_loss_kernel<<<B_DIM, NTHREADS, 0, stream>>>(scores, targets, out);
}